// Round 4
// baseline (17.225 us; speedup 1.0000x reference)
//
#include <hip/hip_runtime.h>
#include <math.h>

#define EPSV 1e-6f

typedef short bf16x8 __attribute__((ext_vector_type(8)));
typedef float f32x4 __attribute__((ext_vector_type(4)));

// round-to-nearest-even f32 -> bf16 bits
static __device__ __forceinline__ short f2bf(float f) {
    unsigned u = __builtin_bit_cast(unsigned, f);
    unsigned r = u + 0x7FFFu + ((u >> 16) & 1u);
    return (short)(r >> 16);
}
static __device__ __forceinline__ float bf2f(short s) {
    return __builtin_bit_cast(float, ((unsigned)(unsigned short)s) << 16);
}

// ---------------------------------------------------------------------------
// prep_w (dest-major): thread d produces wfrag dword d (coalesced write).
// wfrag layout (same as validated rounds): element (col o, k) ->
//   quad q = (ks*4 + ct)*64 + lane, lane = (o&15)|(((k>>3)&3)<<4),
//   ks = k>>5, ct = o>>4, short-in-quad = k&7.
// Dword d = q*4 + (k&7)/2 holds elems k (even) and k+1, which come from
//   wv[k%64][o*10 + k/64] and wv[k%64 + 1][same col]   (scramble closed form,
//   k even => k%64 <= 62, (k+1)/64 == k/64).
// ---------------------------------------------------------------------------
__global__ __launch_bounds__(256) void prep_w(const float* __restrict__ wv,
                                              unsigned* __restrict__ wfrag) {
    int d = blockIdx.x * 256 + threadIdx.x;  // 0..20479
    int q = d >> 2, e2 = d & 3;
    int lane = q & 63, ksct = q >> 6;
    int ct = ksct & 3, ks = ksct >> 2;
    int o = ct * 16 + (lane & 15);
    int k = ks * 32 + ((lane >> 4) & 3) * 8 + e2 * 2;
    int c = o * 10 + (k >> 6);
    int r = k & 63;
    float lo = wv[r * 640 + c];
    float hi = wv[r * 640 + 640 + c];
    wfrag[d] = ((unsigned)(unsigned short)f2bf(lo)) |
               (((unsigned)(unsigned short)f2bf(hi)) << 16);
}

// ---------------------------------------------------------------------------
// fused: norms + MFMA dots + nw2 + distance epilogue.
// grid 256 (rowtile of 16), block 1024 = 16 waves: wave w -> ct = w&3,
// kseg = w>>2 (160 k each, 5 ksteps). 4 waves/SIMD. x read once from HBM
// (ct-waves share chunks via L1/L2). Partial accs/norms combined in LDS.
// ||w_o||^2 computed from the b-fragments already in registers.
// C/D layout (HW-verified): col = lane&15, row = (lane>>4)*4 + reg.
// ---------------------------------------------------------------------------
__global__ __launch_bounds__(1024, 4) void fused(
    const float* __restrict__ x, const unsigned* __restrict__ wfrag,
    const float* __restrict__ temp, float* __restrict__ out) {
    __shared__ f32x4 ldsacc[3][4][64];  // kseg 1..3 parked accs
    __shared__ float2 ldsn[4][16];      // (sum x^2, sum x) per kseg, row
    __shared__ float ldsnw[4][4][16];   // nw partial per kseg, ct, col

    const int tid = threadIdx.x;
    const int l = tid & 63, lm = l & 15, lg = l >> 4;
    const int w = tid >> 6;
    const int ct = w & 3, kseg = w >> 2;
    const int rt = blockIdx.x;

    const float* xr = x + (rt * 16 + lm) * 640 + kseg * 160 + lg * 8;
    const bf16x8* wf = (const bf16x8*)wfrag;
    const int qb = ((kseg * 5) * 4 + ct) * 64 + l;

    f32x4 acc = {0.f, 0.f, 0.f, 0.f};
    float s2 = 0.f, sv = 0.f, nw = 0.f;
#pragma unroll
    for (int s = 0; s < 5; ++s) {
        float4 a0 = *(const float4*)(xr + s * 32);
        float4 a1 = *(const float4*)(xr + s * 32 + 4);
        bf16x8 b = wf[qb + s * 256];
        bf16x8 a;
        a[0] = f2bf(a0.x); a[1] = f2bf(a0.y); a[2] = f2bf(a0.z); a[3] = f2bf(a0.w);
        a[4] = f2bf(a1.x); a[5] = f2bf(a1.y); a[6] = f2bf(a1.z); a[7] = f2bf(a1.w);
        s2 += a0.x * a0.x + a0.y * a0.y + a0.z * a0.z + a0.w * a0.w
            + a1.x * a1.x + a1.y * a1.y + a1.z * a1.z + a1.w * a1.w;
        sv += (a0.x + a0.y + a0.z + a0.w) + (a1.x + a1.y + a1.z + a1.w);
#pragma unroll
        for (int e = 0; e < 8; ++e) { float bw = bf2f(b[e]); nw += bw * bw; }
        acc = __builtin_amdgcn_mfma_f32_16x16x32_bf16(a, b, acc, 0, 0, 0);
    }

    // reduce partials across the 4 lg groups (lanes sharing lm)
    s2 += __shfl_xor(s2, 16); s2 += __shfl_xor(s2, 32);
    sv += __shfl_xor(sv, 16); sv += __shfl_xor(sv, 32);
    nw += __shfl_xor(nw, 16); nw += __shfl_xor(nw, 32);
    if (lg == 0) {
        ldsnw[kseg][ct][lm] = nw;
        if (ct == 0) ldsn[kseg][lm] = make_float2(s2, sv);
    }
    if (kseg > 0) ldsacc[kseg - 1][ct][l] = acc;
    __syncthreads();

    if (kseg == 0) {
#pragma unroll
        for (int p = 0; p < 3; ++p) {
            f32x4 t = ldsacc[p][ct][l];
            acc[0] += t[0]; acc[1] += t[1]; acc[2] += t[2]; acc[3] += t[3];
        }
        float nwv = ldsnw[0][ct][lm] + ldsnw[1][ct][lm] +
                    ldsnw[2][ct][lm] + ldsnw[3][ct][lm];
        float tv = temp[0];
#pragma unroll
        for (int i = 0; i < 4; ++i) {
            int rr = lg * 4 + i;
            float2 n0 = ldsn[0][rr], n1 = ldsn[1][rr];
            float2 n2 = ldsn[2][rr], n3 = ldsn[3][rr];
            float S2 = n0.x + n1.x + n2.x + n3.x;   // sum x^2
            float SV = n0.y + n1.y + n2.y + n3.y;   // sum x
            // ||x+eps||^2 = S2 + 2*eps*SV + 640*eps^2 (exact expansion)
            float S1 = S2 + 2.f * EPSV * SV + 640.f * EPSV * EPSV;
            float iv = rsqrtf(S1);
            float nx = S2 * iv * iv;                // ||xn||^2
            float d2 = nx - 2.f * acc[i] * iv + nwv;
            out[(rt * 16 + rr) * 64 + ct * 16 + lm] = tv * sqrtf(fmaxf(d2, 0.f));
        }
    }
}

extern "C" void kernel_launch(void* const* d_in, const int* in_sizes, int n_in,
                              void* d_out, int out_size, void* d_ws, size_t ws_size,
                              hipStream_t stream) {
    const float* x = (const float*)d_in[0];     // [4096, 640]
    const float* wv = (const float*)d_in[1];    // [64, 640]
    const float* temp = (const float*)d_in[2];  // [1]
    float* out = (float*)d_out;                 // [4096, 64]

    unsigned* wfrag = (unsigned*)d_ws;          // 20480 dwords = 81920 B

    prep_w<<<80, 256, 0, stream>>>(wv, wfrag);
    fused<<<256, 1024, 0, stream>>>(x, wfrag, temp, out);
}

// Round 5
// 16.802 us; speedup vs baseline: 1.0251x; 1.0251x over previous
//
#include <hip/hip_runtime.h>
#include <math.h>

#define EPSV 1e-6f

typedef short bf16x8 __attribute__((ext_vector_type(8)));
typedef float f32x4 __attribute__((ext_vector_type(4)));

// round-to-nearest-even f32 -> bf16 bits
static __device__ __forceinline__ short f2bf(float f) {
    unsigned u = __builtin_bit_cast(unsigned, f);
    unsigned r = u + 0x7FFFu + ((u >> 16) & 1u);
    return (short)(r >> 16);
}
static __device__ __forceinline__ float bf2f(short s) {
    return __builtin_bit_cast(float, ((unsigned)(unsigned short)s) << 16);
}

// ---------------------------------------------------------------------------
// Single fused kernel.
// Phase 0 (staging): every block converts scrambled wv (f32 [64][640],
//   w[o][k] = wv[k%64][o*10 + k/64]) into an 80KB LDS bf16 B-fragment array.
//   Thread tid reads wv row r=tid>>4, cols c=(tid&15)*40 + m (m=0..39) --
//   fully coalesced (40 consecutive floats/thread). Fragment address of
//   element (o = c/10, k = (c%10)*64 + r):
//     byte = (k>>5)*4096 + (o>>4)*1024 + (o&15)*16 + ((k>>3)&3)*256 + (k&7)*2
//   With this mapping: o&15 = (tid&3)*4 + m/10, (k>>3)&3 = (r>>3)&3,
//   k&7 = r&7, k>>5 = (m%10)*2 + (r>>5), o>>4 = (tid&15)>>2  -- so the
//   address is a per-thread base + compile-time (m%10)*8192 + (m/10)*16.
// Phase 1 (hot loop): round-4 validated structure. 16 waves = (ct 0..3) x
//   (kseg 0..3), 5 ksteps each; A built in-register from global x; B via
//   ds_read_b128 from the staged LDS fragments; norms + ||w_o||^2 from the
//   same registers; LDS combine; distance epilogue.
// C/D layout (HW-verified): col = lane&15, row = (lane>>4)*4 + reg.
// ---------------------------------------------------------------------------
__global__ __launch_bounds__(1024) void fused_all(
    const float* __restrict__ x, const float* __restrict__ wv,
    const float* __restrict__ temp, float* __restrict__ out) {
    __shared__ __align__(16) short wf[40960];  // 80 KB fragment-layout w
    __shared__ f32x4 ldsacc[3][4][64];         // kseg 1..3 parked accs
    __shared__ float2 ldsn[4][16];             // (sum x^2, sum x) per kseg,row
    __shared__ float ldsnw[4][4][16];          // nw partial per kseg,ct,col

    const int tid = threadIdx.x;

    // ---- Phase 0: stage wv -> wf ----
    {
        const int t15 = tid & 15;
        const int r = tid >> 4;  // wv row = k % 64
        const float4* wrow = (const float4*)wv + tid * 10;
        char* wfb = (char*)wf + (r >> 5) * 4096     // k>>5 low bit (from r)
                    + (t15 >> 2) * 1024             // o>>4 (ct)
                    + ((t15 & 3) * 4) * 16          // o&15 base
                    + (((r >> 3) & 3)) * 256        // (k>>3)&3 lane-high
                    + (r & 7) * 2;                  // k&7
#pragma unroll
        for (int q = 0; q < 10; ++q) {
            float4 v = wrow[q];
            float vals[4] = {v.x, v.y, v.z, v.w};
#pragma unroll
            for (int e2 = 0; e2 < 4; ++e2) {
                const int m = q * 4 + e2;           // 0..39, compile-time
                const int md = m / 10;              // adds to o&15
                const int mm = m % 10;              // adds 2 to k>>5
                *(short*)(wfb + mm * 8192 + md * 16) = f2bf(vals[e2]);
            }
        }
    }
    __syncthreads();

    // ---- Phase 1: hot loop (round-4 structure, B from LDS) ----
    const int l = tid & 63, lm = l & 15, lg = l >> 4;
    const int w = tid >> 6;
    const int ct = w & 3, kseg = w >> 2;
    const int rt = blockIdx.x;

    const float* xr = x + (rt * 16 + lm) * 640 + kseg * 160 + lg * 8;
    const bf16x8* wfq = (const bf16x8*)wf;
    const int qb = ((kseg * 5) * 4 + ct) * 64 + l;

    f32x4 acc = {0.f, 0.f, 0.f, 0.f};
    float s2 = 0.f, sv = 0.f, nw = 0.f;
#pragma unroll
    for (int s = 0; s < 5; ++s) {
        float4 a0 = *(const float4*)(xr + s * 32);
        float4 a1 = *(const float4*)(xr + s * 32 + 4);
        bf16x8 b = wfq[qb + s * 256];
        bf16x8 a;
        a[0] = f2bf(a0.x); a[1] = f2bf(a0.y); a[2] = f2bf(a0.z); a[3] = f2bf(a0.w);
        a[4] = f2bf(a1.x); a[5] = f2bf(a1.y); a[6] = f2bf(a1.z); a[7] = f2bf(a1.w);
        s2 += a0.x * a0.x + a0.y * a0.y + a0.z * a0.z + a0.w * a0.w
            + a1.x * a1.x + a1.y * a1.y + a1.z * a1.z + a1.w * a1.w;
        sv += (a0.x + a0.y + a0.z + a0.w) + (a1.x + a1.y + a1.z + a1.w);
#pragma unroll
        for (int e = 0; e < 8; ++e) { float bw = bf2f(b[e]); nw += bw * bw; }
        acc = __builtin_amdgcn_mfma_f32_16x16x32_bf16(a, b, acc, 0, 0, 0);
    }

    // reduce partials across the 4 lg groups (lanes sharing lm)
    s2 += __shfl_xor(s2, 16); s2 += __shfl_xor(s2, 32);
    sv += __shfl_xor(sv, 16); sv += __shfl_xor(sv, 32);
    nw += __shfl_xor(nw, 16); nw += __shfl_xor(nw, 32);
    if (lg == 0) {
        ldsnw[kseg][ct][lm] = nw;
        if (ct == 0) ldsn[kseg][lm] = make_float2(s2, sv);
    }
    if (kseg > 0) ldsacc[kseg - 1][ct][l] = acc;
    __syncthreads();

    if (kseg == 0) {
#pragma unroll
        for (int p = 0; p < 3; ++p) {
            f32x4 t = ldsacc[p][ct][l];
            acc[0] += t[0]; acc[1] += t[1]; acc[2] += t[2]; acc[3] += t[3];
        }
        float nwv = ldsnw[0][ct][lm] + ldsnw[1][ct][lm] +
                    ldsnw[2][ct][lm] + ldsnw[3][ct][lm];
        float tv = temp[0];
#pragma unroll
        for (int i = 0; i < 4; ++i) {
            int rr = lg * 4 + i;
            float2 n0 = ldsn[0][rr], n1 = ldsn[1][rr];
            float2 n2 = ldsn[2][rr], n3 = ldsn[3][rr];
            float S2 = n0.x + n1.x + n2.x + n3.x;   // sum x^2
            float SV = n0.y + n1.y + n2.y + n3.y;   // sum x
            // ||x+eps||^2 = S2 + 2*eps*SV + 640*eps^2 (exact expansion)
            float S1 = S2 + 2.f * EPSV * SV + 640.f * EPSV * EPSV;
            float iv = rsqrtf(S1);
            float nx = S2 * iv * iv;                // ||xn||^2
            float d2 = nx - 2.f * acc[i] * iv + nwv;
            out[(rt * 16 + rr) * 64 + ct * 16 + lm] = tv * sqrtf(fmaxf(d2, 0.f));
        }
    }
}

extern "C" void kernel_launch(void* const* d_in, const int* in_sizes, int n_in,
                              void* d_out, int out_size, void* d_ws, size_t ws_size,
                              hipStream_t stream) {
    const float* x = (const float*)d_in[0];     // [4096, 640]
    const float* wv = (const float*)d_in[1];    // [64, 640]
    const float* temp = (const float*)d_in[2];  // [1]
    float* out = (float*)d_out;                 // [4096, 64]

    fused_all<<<256, 1024, 0, stream>>>(x, wv, temp, out);
}

// Round 6
// 14.199 us; speedup vs baseline: 1.2131x; 1.1834x over previous
//
#include <hip/hip_runtime.h>
#include <math.h>

typedef short bf16x8 __attribute__((ext_vector_type(8)));
typedef float f32x4 __attribute__((ext_vector_type(4)));

// packed f32x2 -> bf16x2 (RNE on gfx950); guide T12/m240-verified mnemonic
static __device__ __forceinline__ unsigned cvt_pk_bf16(float lo, float hi) {
    unsigned r;
    asm("v_cvt_pk_bf16_f32 %0, %1, %2" : "=v"(r) : "v"(lo), "v"(hi));
    return r;
}

// ---------------------------------------------------------------------------
// Single fused kernel, grid 256 x 1024 threads (16 waves = ct 0..3 x kseg 0..3).
//
// Fragment byte address (validated r2-r5; spot-check (o=17,k=100) -> 13336):
//   byte(o,k) = (k>>5)*4096 + (o>>4)*1024 + (o&15)*16 + ((k>>3)&3)*256 + (k&7)*2
// Scramble closed form: w[o][k] = wv[k%64][o*10 + k/64]   (640 = 64*10)
//
// Phase A: issue all x loads into regs (xa[10], static-indexed) -> HBM stream
//          overlaps Phase B.
// Phase B: stage wv -> LDS fragments. Thread item (rp 0..31, cg 0..63): rows
//          {2rp, 2rp+1}, cols 10cg..10cg+9. k = 64*dc + 2rp + dr:
//            k&7 = 2(rp&3)+dr  -> row-pair packs into ONE aligned b32
//            (k>>3)&3 = (rp>>2)&3,  k>>5 = 2dc + (rp>>4)
//          write dword = base + dc*8192, base = (rp>>4)*4096 + (cg>>4)*1024
//            + (cg&15)*16 + ((rp>>2)&3)*256 + 4(rp&3)
//          bank = 4(cg&7) + (rp&3): lane bits {0-2}=cg0-2, {3-4}=rp0-1 span all
//          32 banks -> 2-way only (free). 2 items/thread via it-loop (rp bit 4).
// Phase C: hot loop. B via ds_read_b128; A via cvt_pk from resident xa;
//          3 MFMAs/kstep: dot, gramW = b.b^T (diag = ||w_o||^2), and for ct==0
//          gramX = a.a^T (diag = ||x_r||^2). Same k-permutation on both
//          operands => permutation cancels; gram diag is exact bf16 gram.
// Phase D: diag lanes (lm>>2==lg) write norms; kseg>0 park acc; combine:
//          out = temp * sqrt(1 - 2*dot*rsqrt(S2) + nw)   [nx == 1 exactly
//          since we drop 2*eps*Sx ~ 4e-7 relative -- invisible at bf16 scale]
// C/D layout (HW-verified): col = lane&15, row = (lane>>4)*4 + reg.
// ---------------------------------------------------------------------------
__global__ __launch_bounds__(1024) void fused_all(
    const float* __restrict__ x, const float* __restrict__ wv,
    const float* __restrict__ temp, float* __restrict__ out) {
    __shared__ __align__(16) short wf[40960];  // 80 KB fragment-layout w
    __shared__ f32x4 ldsacc[3][4][64];         // kseg 1..3 parked accs (12 KB)
    __shared__ float ldsn[4][16];              // ||x_r||^2 partial per kseg
    __shared__ float ldsnw[4][4][16];          // ||w_o||^2 partial per kseg,ct

    const int tid = threadIdx.x;
    const int l = tid & 63, lm = l & 15, lg = l >> 4;
    const int w = tid >> 6;
    const int ct = w & 3, kseg = w >> 2;
    const int rt = blockIdx.x;

    // ---- Phase A: issue x loads, hold in regs ----
    const float* xr = x + (rt * 16 + lm) * 640 + kseg * 160 + lg * 8;
    float4 xa[10];
#pragma unroll
    for (int s = 0; s < 5; ++s) {
        xa[2 * s]     = *(const float4*)(xr + s * 32);
        xa[2 * s + 1] = *(const float4*)(xr + s * 32 + 4);
    }
    float tv = temp[0];

    // ---- Phase B: stage wv -> wf ----
#pragma unroll
    for (int it = 0; it < 2; ++it) {
        const int cg = (tid & 7) | (((tid >> 5) & 7) << 3);
        const int rp = ((tid >> 3) & 3) | (((tid >> 8) & 3) << 2) | (it << 4);
        const float* r0 = wv + (2 * rp) * 640 + 10 * cg;
        const float* r1 = r0 + 640;
        char* base = (char*)wf + (rp >> 4) * 4096 + (cg >> 4) * 1024 +
                     (cg & 15) * 16 + ((rp >> 2) & 3) * 256 + 4 * (rp & 3);
#pragma unroll
        for (int j = 0; j < 5; ++j) {
            float2 va = *(const float2*)(r0 + 2 * j);
            float2 vb = *(const float2*)(r1 + 2 * j);
            *(unsigned*)(base + (2 * j) * 8192)     = cvt_pk_bf16(va.x, vb.x);
            *(unsigned*)(base + (2 * j + 1) * 8192) = cvt_pk_bf16(va.y, vb.y);
        }
    }
    __syncthreads();

    // ---- Phase C: hot loop ----
    const bf16x8* wfq = (const bf16x8*)wf;
    const int qb = (kseg * 20 + ct) * 64 + l;

    f32x4 acc  = {0.f, 0.f, 0.f, 0.f};
    f32x4 accW = {0.f, 0.f, 0.f, 0.f};
    f32x4 accG = {0.f, 0.f, 0.f, 0.f};
#pragma unroll
    for (int s = 0; s < 5; ++s) {
        bf16x8 b = wfq[qb + s * 256];
        float4 a0 = xa[2 * s], a1 = xa[2 * s + 1];
        union { unsigned u[4]; bf16x8 v; } A;
        A.u[0] = cvt_pk_bf16(a0.x, a0.y);
        A.u[1] = cvt_pk_bf16(a0.z, a0.w);
        A.u[2] = cvt_pk_bf16(a1.x, a1.y);
        A.u[3] = cvt_pk_bf16(a1.z, a1.w);
        acc  = __builtin_amdgcn_mfma_f32_16x16x32_bf16(A.v, b, acc, 0, 0, 0);
        accW = __builtin_amdgcn_mfma_f32_16x16x32_bf16(b, b, accW, 0, 0, 0);
        if (ct == 0)
            accG = __builtin_amdgcn_mfma_f32_16x16x32_bf16(A.v, A.v, accG, 0, 0, 0);
    }

    // ---- Phase D: norms to LDS, park accs, combine ----
    if ((lm >> 2) == lg) {            // lane holds gram diagonal element lm
        ldsnw[kseg][ct][lm] = accW[lm & 3];
        if (ct == 0) ldsn[kseg][lm] = accG[lm & 3];
    }
    if (kseg > 0) ldsacc[kseg - 1][ct][l] = acc;
    __syncthreads();

    if (kseg == 0) {
#pragma unroll
        for (int p = 0; p < 3; ++p) {
            f32x4 t2 = ldsacc[p][ct][l];
            acc[0] += t2[0]; acc[1] += t2[1]; acc[2] += t2[2]; acc[3] += t2[3];
        }
        float nwv = ldsnw[0][ct][lm] + ldsnw[1][ct][lm] +
                    ldsnw[2][ct][lm] + ldsnw[3][ct][lm];
#pragma unroll
        for (int i = 0; i < 4; ++i) {
            int rr = lg * 4 + i;
            float S2 = ldsn[0][rr] + ldsn[1][rr] + ldsn[2][rr] + ldsn[3][rr];
            float iv = rsqrtf(S2);
            float d2 = 1.0f - 2.f * acc[i] * iv + nwv;
            out[(rt * 16 + rr) * 64 + ct * 16 + lm] = tv * sqrtf(fmaxf(d2, 0.f));
        }
    }
}

extern "C" void kernel_launch(void* const* d_in, const int* in_sizes, int n_in,
                              void* d_out, int out_size, void* d_ws, size_t ws_size,
                              hipStream_t stream) {
    const float* x = (const float*)d_in[0];     // [4096, 640]
    const float* wv = (const float*)d_in[1];    // [64, 640]
    const float* temp = (const float*)d_in[2];  // [1]
    float* out = (float*)d_out;                 // [4096, 64]

    fused_all<<<256, 1024, 0, stream>>>(x, wv, temp, out);
}

// Round 7
// 13.714 us; speedup vs baseline: 1.2560x; 1.0353x over previous
//
#include <hip/hip_runtime.h>
#include <math.h>

typedef short bf16x8 __attribute__((ext_vector_type(8)));
typedef float f32x4 __attribute__((ext_vector_type(4)));

// packed f32x2 -> bf16x2 (RNE on gfx950); guide T12/m240-verified mnemonic
static __device__ __forceinline__ unsigned cvt_pk_bf16(float lo, float hi) {
    unsigned r;
    asm("v_cvt_pk_bf16_f32 %0, %1, %2" : "=v"(r) : "v"(lo), "v"(hi));
    return r;
}

// ---------------------------------------------------------------------------
// Single fused kernel, grid 256 x 1024 threads (16 waves = ct 0..3 x kseg 0..3).
//
// Fragment byte address (validated r2-r6):
//   byte(o,k) = (k>>5)*4096 + (o>>4)*1024 + (o&15)*16 + ((k>>3)&3)*256 + (k&7)*2
// Scramble closed form: w[o][k] = wv[k%64][o*10 + k/64]   (640 = 64*10)
//
// ISSUE ORDER (the r7 change): vmcnt retires IN ORDER, so older loads gate
// younger waits. r6 issued x (HBM-slow) before wv (L2-fast), making the
// staging cvt_pk wait on the whole x stream. Now: (1) issue 20 wv loads into
// regs, (2) issue 10 x loads into regs, (3) stage (waits wv only; x stream
// completes under staging+barrier), (4) hot loop (x already retired).
//
// Staging mapping (validated r6): thread item (rp 0..31, cg 0..63) covers wv
// rows {2rp,2rp+1} x cols 10cg..10cg+9; k = 64*dc + 2rp + dr packs the row
// pair into one aligned b32 (k&7 = 2(rp&3)+dr); write dword = base + dc*8192;
// bank = 4(cg&7)+(rp&3) spans all 32 banks -> 2-way only (free).
// Hot loop: B via ds_read_b128; A via cvt_pk from resident xa; 3 MFMAs/kstep:
// dot, gramW=b.b^T (diag=||w_o||^2), ct==0 also gramX=a.a^T (diag=||x_r||^2).
// Same k-permutation on both operands => permutation cancels, diag exact.
// Epilogue: out = temp * sqrt(1 - 2*dot*rsqrt(S2) + nw)  [nx==1 exactly;
// dropped 2*eps*Sx ~ 4e-7 relative, invisible at bf16 scale].
// C/D layout (HW-verified): col = lane&15, row = (lane>>4)*4 + reg.
// ---------------------------------------------------------------------------
__global__ __launch_bounds__(1024) void fused_all(
    const float* __restrict__ x, const float* __restrict__ wv,
    const float* __restrict__ temp, float* __restrict__ out) {
    __shared__ __align__(16) short wf[40960];  // 80 KB fragment-layout w
    __shared__ f32x4 ldsacc[3][4][64];         // kseg 1..3 parked accs (12 KB)
    __shared__ float ldsn[4][16];              // ||x_r||^2 partial per kseg
    __shared__ float ldsnw[4][4][16];          // ||w_o||^2 partial per kseg,ct

    const int tid = threadIdx.x;
    const int l = tid & 63, lm = l & 15, lg = l >> 4;
    const int w = tid >> 6;
    const int ct = w & 3, kseg = w >> 2;
    const int rt = blockIdx.x;

    // ---- (1) issue wv loads first (L2-fast; statically indexed regs) ----
    const int cg = (tid & 7) | (((tid >> 5) & 7) << 3);
    const int rp0 = ((tid >> 3) & 3) | (((tid >> 8) & 3) << 2);
    float2 va[2][5], vb[2][5];
#pragma unroll
    for (int it = 0; it < 2; ++it) {
        const int rp = rp0 | (it << 4);
        const float* r0 = wv + (2 * rp) * 640 + 10 * cg;
        const float* r1 = r0 + 640;
#pragma unroll
        for (int j = 0; j < 5; ++j) {
            va[it][j] = *(const float2*)(r0 + 2 * j);
            vb[it][j] = *(const float2*)(r1 + 2 * j);
        }
    }

    // ---- (2) issue x loads (HBM; complete under staging+barrier) ----
    const float* xr = x + (rt * 16 + lm) * 640 + kseg * 160 + lg * 8;
    float4 xa[10];
#pragma unroll
    for (int s = 0; s < 5; ++s) {
        xa[2 * s]     = *(const float4*)(xr + s * 32);
        xa[2 * s + 1] = *(const float4*)(xr + s * 32 + 4);
    }
    float tv = temp[0];

    // ---- (3) stage wv -> wf (waits only wv loads, in issue order) ----
#pragma unroll
    for (int it = 0; it < 2; ++it) {
        const int rp = rp0 | (it << 4);
        char* base = (char*)wf + (rp >> 4) * 4096 + (cg >> 4) * 1024 +
                     (cg & 15) * 16 + ((rp >> 2) & 3) * 256 + 4 * (rp & 3);
#pragma unroll
        for (int j = 0; j < 5; ++j) {
            *(unsigned*)(base + (2 * j) * 8192) =
                cvt_pk_bf16(va[it][j].x, vb[it][j].x);
            *(unsigned*)(base + (2 * j + 1) * 8192) =
                cvt_pk_bf16(va[it][j].y, vb[it][j].y);
        }
    }
    __syncthreads();

    // ---- (4) hot loop ----
    const bf16x8* wfq = (const bf16x8*)wf;
    const int qb = (kseg * 20 + ct) * 64 + l;

    f32x4 acc  = {0.f, 0.f, 0.f, 0.f};
    f32x4 accW = {0.f, 0.f, 0.f, 0.f};
    f32x4 accG = {0.f, 0.f, 0.f, 0.f};
#pragma unroll
    for (int s = 0; s < 5; ++s) {
        bf16x8 b = wfq[qb + s * 256];
        float4 a0 = xa[2 * s], a1 = xa[2 * s + 1];
        union { unsigned u[4]; bf16x8 v; } A;
        A.u[0] = cvt_pk_bf16(a0.x, a0.y);
        A.u[1] = cvt_pk_bf16(a0.z, a0.w);
        A.u[2] = cvt_pk_bf16(a1.x, a1.y);
        A.u[3] = cvt_pk_bf16(a1.z, a1.w);
        acc  = __builtin_amdgcn_mfma_f32_16x16x32_bf16(A.v, b, acc, 0, 0, 0);
        accW = __builtin_amdgcn_mfma_f32_16x16x32_bf16(b, b, accW, 0, 0, 0);
        if (ct == 0)
            accG = __builtin_amdgcn_mfma_f32_16x16x32_bf16(A.v, A.v, accG, 0, 0, 0);
    }

    // ---- norms to LDS, park accs, combine ----
    if ((lm >> 2) == lg) {            // lane holds gram diagonal element lm
        ldsnw[kseg][ct][lm] = accW[lm & 3];
        if (ct == 0) ldsn[kseg][lm] = accG[lm & 3];
    }
    if (kseg > 0) ldsacc[kseg - 1][ct][l] = acc;
    __syncthreads();

    if (kseg == 0) {
#pragma unroll
        for (int p = 0; p < 3; ++p) {
            f32x4 t2 = ldsacc[p][ct][l];
            acc[0] += t2[0]; acc[1] += t2[1]; acc[2] += t2[2]; acc[3] += t2[3];
        }
        float nwv = ldsnw[0][ct][lm] + ldsnw[1][ct][lm] +
                    ldsnw[2][ct][lm] + ldsnw[3][ct][lm];
#pragma unroll
        for (int i = 0; i < 4; ++i) {
            int rr = lg * 4 + i;
            float S2 = ldsn[0][rr] + ldsn[1][rr] + ldsn[2][rr] + ldsn[3][rr];
            float iv = rsqrtf(S2);
            float d2 = 1.0f - 2.f * acc[i] * iv + nwv;
            out[(rt * 16 + rr) * 64 + ct * 16 + lm] = tv * sqrtf(fmaxf(d2, 0.f));
        }
    }
}

extern "C" void kernel_launch(void* const* d_in, const int* in_sizes, int n_in,
                              void* d_out, int out_size, void* d_ws, size_t ws_size,
                              hipStream_t stream) {
    const float* x = (const float*)d_in[0];     // [4096, 640]
    const float* wv = (const float*)d_in[1];    // [64, 640]
    const float* temp = (const float*)d_in[2];  // [1]
    float* out = (float*)d_out;                 // [4096, 64]

    fused_all<<<256, 1024, 0, stream>>>(x, wv, temp, out);
}

// Round 8
// 13.560 us; speedup vs baseline: 1.2702x; 1.0113x over previous
//
#include <hip/hip_runtime.h>
#include <math.h>

typedef short bf16x8 __attribute__((ext_vector_type(8)));
typedef float f32x4 __attribute__((ext_vector_type(4)));

// packed f32x2 -> bf16x2 (RNE on gfx950); guide T12/m240-verified mnemonic
static __device__ __forceinline__ unsigned cvt_pk_bf16(float lo, float hi) {
    unsigned r;
    asm("v_cvt_pk_bf16_f32 %0, %1, %2" : "=v"(r) : "v"(lo), "v"(hi));
    return r;
}

// ---------------------------------------------------------------------------
// Grid 1024 = ct(4) x rt(256), bid = ct*256 + rt so the 4 ct-blocks of one
// rowtile land on the SAME XCD (round-robin bid%8 = rt%8) and share x via
// that XCD's L2. Block = 256 threads = 4 waves (kseg 0..3, 160 k each).
// Each block computes a 16-row x 16-col output tile over full K, staging only
// ITS 16 w-columns (20 KB LDS) -> 4 independent blocks resident per CU
// (24 KB LDS, 4 waves/SIMD): staging of one block overlaps hot loops of
// others (no 16-wave convoy).
//
// Scramble closed form: w[o][k] = wv[k%64][o*10 + k/64]  (640 = 64*10)
// Block-local fragment address (o = 16ct + cg, cg = o&15):
//   byte(o,k) = (k>>5)*1024 + ((k>>3)&3)*256 + (o&15)*16 + (k&7)*2
// Staging item (rp 0..31, cg 0..15): wv rows {2rp,2rp+1} x cols
// (16ct+cg)*10 .. +9. With k = 64*dc + 2rp + dr:
//   k&7 = 2(rp&3)+dr  -> row pair packs into one aligned b32
//   (k>>3)&3 = (rp>>2)&3,  k>>5 = 2dc + (rp>>4)
//   dword byte = base + dc*2048, base = (rp>>4)*1024 + ((rp>>2)&3)*256
//                + cg*16 + 4(rp&3)
//   bank = 4(cg&7) + (rp&3): lane bits 0-2 (cg) x 4-5 (rp) span all 32 banks
//   -> 2-way only (free, m136).
// ISSUE ORDER (r7-validated): wv loads first, x loads second; staging waits
// only on the older wv group (vmcnt retires in order); the x HBM stream
// completes under staging + barrier.
// Hot loop: B via ds_read_b128 (lane l reads quad l -> conflict-free);
// A via cvt_pk from resident xa; 3 MFMAs/kstep: dot, gramW = b.b^T
// (diag = ||w_o||^2), gramX = a.a^T (diag = ||x_r||^2). Same k-permutation on
// both operands => permutation cancels; diagonals are exact bf16 norms.
// Epilogue: out = temp * sqrt(1 - 2*dot*rsqrt(S2) + nw)   [||xn||^2 == 1
// exactly; dropped 2*eps*sum(x) ~ 4e-7 relative -- invisible at bf16 scale]
// C/D layout (HW-verified): col = lane&15, row = (lane>>4)*4 + reg.
// ---------------------------------------------------------------------------
__global__ __launch_bounds__(256, 4) void fused_all(
    const float* __restrict__ x, const float* __restrict__ wv,
    const float* __restrict__ temp, float* __restrict__ out) {
    __shared__ __align__(16) short wf[10240];  // 20 KB fragment-layout w cols
    __shared__ f32x4 ldsacc[3][64];            // kseg 1..3 parked accs (3 KB)
    __shared__ float ldsn[4][16];              // ||x_r||^2 partial per kseg
    __shared__ float ldsnw[4][16];             // ||w_o||^2 partial per kseg

    const int tid = threadIdx.x;
    const int l = tid & 63, lm = l & 15, lg = l >> 4;
    const int kseg = tid >> 6;
    const int bid = blockIdx.x;
    const int rt = bid & 255, ct = bid >> 8;

    // ---- (1) issue wv loads first (L2-fast; statically indexed regs) ----
    const int cg = tid & 15;
    const int rp0 = (tid >> 4) & 15;
    float2 va[2][5], vb[2][5];
#pragma unroll
    for (int it = 0; it < 2; ++it) {
        const int rp = rp0 | (it << 4);
        const float* r0 = wv + (2 * rp) * 640 + (16 * ct + cg) * 10;
        const float* r1 = r0 + 640;
#pragma unroll
        for (int j = 0; j < 5; ++j) {
            va[it][j] = *(const float2*)(r0 + 2 * j);
            vb[it][j] = *(const float2*)(r1 + 2 * j);
        }
    }

    // ---- (2) issue x loads (HBM; complete under staging+barrier) ----
    const float* xr = x + (rt * 16 + lm) * 640 + kseg * 160 + lg * 8;
    float4 xa[10];
#pragma unroll
    for (int s = 0; s < 5; ++s) {
        xa[2 * s]     = *(const float4*)(xr + s * 32);
        xa[2 * s + 1] = *(const float4*)(xr + s * 32 + 4);
    }
    float tv = temp[0];

    // ---- (3) stage wv -> wf (waits only wv loads, in issue order) ----
#pragma unroll
    for (int it = 0; it < 2; ++it) {
        const int rp = rp0 | (it << 4);
        char* base = (char*)wf + (rp >> 4) * 1024 + ((rp >> 2) & 3) * 256 +
                     cg * 16 + 4 * (rp & 3);
#pragma unroll
        for (int j = 0; j < 5; ++j) {
            *(unsigned*)(base + (2 * j) * 2048) =
                cvt_pk_bf16(va[it][j].x, vb[it][j].x);
            *(unsigned*)(base + (2 * j + 1) * 2048) =
                cvt_pk_bf16(va[it][j].y, vb[it][j].y);
        }
    }
    __syncthreads();

    // ---- (4) hot loop ----
    const bf16x8* wfq = (const bf16x8*)wf;
    const int qb = kseg * 5 * 64 + l;

    f32x4 acc  = {0.f, 0.f, 0.f, 0.f};
    f32x4 accW = {0.f, 0.f, 0.f, 0.f};
    f32x4 accG = {0.f, 0.f, 0.f, 0.f};
#pragma unroll
    for (int s = 0; s < 5; ++s) {
        bf16x8 b = wfq[qb + s * 64];
        float4 a0 = xa[2 * s], a1 = xa[2 * s + 1];
        union { unsigned u[4]; bf16x8 v; } A;
        A.u[0] = cvt_pk_bf16(a0.x, a0.y);
        A.u[1] = cvt_pk_bf16(a0.z, a0.w);
        A.u[2] = cvt_pk_bf16(a1.x, a1.y);
        A.u[3] = cvt_pk_bf16(a1.z, a1.w);
        acc  = __builtin_amdgcn_mfma_f32_16x16x32_bf16(A.v, b, acc, 0, 0, 0);
        accW = __builtin_amdgcn_mfma_f32_16x16x32_bf16(b, b, accW, 0, 0, 0);
        accG = __builtin_amdgcn_mfma_f32_16x16x32_bf16(A.v, A.v, accG, 0, 0, 0);
    }

    // ---- (5) norms to LDS, park accs, combine ----
    if ((lm >> 2) == lg) {            // lane holds gram diagonal element lm
        ldsnw[kseg][lm] = accW[lm & 3];
        ldsn[kseg][lm]  = accG[lm & 3];
    }
    if (kseg > 0) ldsacc[kseg - 1][l] = acc;
    __syncthreads();

    if (kseg == 0) {
#pragma unroll
        for (int p = 0; p < 3; ++p) {
            f32x4 t2 = ldsacc[p][l];
            acc[0] += t2[0]; acc[1] += t2[1]; acc[2] += t2[2]; acc[3] += t2[3];
        }
        float nwv = ldsnw[0][lm] + ldsnw[1][lm] + ldsnw[2][lm] + ldsnw[3][lm];
#pragma unroll
        for (int i = 0; i < 4; ++i) {
            int rr = lg * 4 + i;
            float S2 = ldsn[0][rr] + ldsn[1][rr] + ldsn[2][rr] + ldsn[3][rr];
            float iv = rsqrtf(S2);
            float d2 = 1.0f - 2.f * acc[i] * iv + nwv;
            out[(rt * 16 + rr) * 64 + ct * 16 + lm] = tv * sqrtf(fmaxf(d2, 0.f));
        }
    }
}

extern "C" void kernel_launch(void* const* d_in, const int* in_sizes, int n_in,
                              void* d_out, int out_size, void* d_ws, size_t ws_size,
                              hipStream_t stream) {
    const float* x = (const float*)d_in[0];     // [4096, 640]
    const float* wv = (const float*)d_in[1];    // [64, 640]
    const float* temp = (const float*)d_in[2];  // [1]
    float* out = (float*)d_out;                 // [4096, 64]

    fused_all<<<1024, 256, 0, stream>>>(x, wv, temp, out);
}